// Round 5
// baseline (608.236 us; speedup 1.0000x reference)
//
#include <hip/hip_runtime.h>

// Multi-scale deformable attention, nearest sampling, zero padding.
// value:             (6, 14960, 8, 32)  f32
// sampling_locations:(6, 40000, 8, 4, 4, 2) f32
// out:               (6, 40000, 256)    f32
//
// Mapping: 8 lanes per (b,q,h) group; lane owns float4 of D (ll = lane&7).
// Gather per sample = one 128B line across the 8 lanes.
//
// Round-5: LDS-stage levels 2+3.
// Evidence R2-R4: per-CU scattered-gather throughput pinned at ~22 B/cy
// (~6cy per 128B line) regardless of MLP depth (16 vs 32) and L2 locality
// (FETCH 840->165MB with zero time change) -> per-CU L1/TA line-service
// wall. Only fix: remove transactions from the vector-L1 path.
// Levels 2+3 of one (b,h) = 880 keys x 128B = 110KB -> fits LDS, serves
// HALF of all samples via the independent LDS pipe (128B/cy, conflict-
// free: each group's 128B row spans all 32 banks).
// Block = 512 thr, one (b,h), 1600 queries (Q=25/group) -> stage
// amortized 14.5x. Grid = 6b x 8h x 25chunks = 1200, XCD-pinned h.
// Global path (levels 0,1) keeps: dedup'd address math + shfl broadcast,
// validity in bit0 of aligned offsets, depth-1 gather / depth-2 loc
// prefetch. Pin-asms dropped (counted waits beat full drains).

#define BS 6
#define NQ 40000
#define NH 8
#define HD 32
#define NK 14960

#define STAGE_KEY0 14080          // first level-2 key
#define STAGE_KEYS 880            // levels 2+3
#define THREADS    512
#define QPT        25             // queries per group (64 groups/block)
#define QPB        1600           // queries per block = 64*QPT

typedef float f32x4 __attribute__((ext_vector_type(4)));

__global__ __launch_bounds__(THREADS, 2)
void msda_kernel(const float* __restrict__ value,
                 const float* __restrict__ loc,
                 float* __restrict__ out) {
    extern __shared__ float lds[];     // 880*32 floats = 112,640 B

    const int t    = threadIdx.x;
    const int ll   = t & 7;            // role within the 8-lane group
    const int gr   = t >> 3;           // group 0..63 in block
    const int lane = t & 63;

    // ---- decomposition: 1200 blocks = 8 xcd * (6 b * 25 chunks) ----
    const int xcd   = blockIdx.x & 7;
    const int seq   = blockIdx.x >> 3;     // 0..149
    const int b     = seq / 25;            // magic-mul
    const int chunk = seq - b * 25;
    const int h     = xcd;
    const int qbase = chunk * QPB;

    const char* vb = (const char*)value;
    // byte offset of (b,key,h,0) = b*NK*1024 + key*1024 + h*128
    const size_t vbh = (size_t)b * (NK * 1024) + (size_t)h * 128;

    // ---- stage keys [14080,14960) of this (b,h) into LDS ----
    {
        const char* src0 = vb + vbh + (size_t)STAGE_KEY0 * 1024;
        #pragma unroll
        for (int k = 0; k < 14; ++k) {
            const int i = t + k * THREADS;        // float4 index, 0..7039
            if (i < STAGE_KEYS * 8) {
                const int key8 = i >> 3, part = i & 7;
                const f32x4 d = *(const f32x4*)(src0 + (size_t)key8 * 1024 + part * 16);
                *(f32x4*)(lds + (size_t)i * 4) = d;
            }
        }
    }
    __syncthreads();

    // ---- per-lane level constants ----
    // loc float4 #ll covers level l = ll>>1, points p = (ll&1)*2 + {0,1}
    // lanes 0-3 -> levels 0,1 (global), lanes 4-7 -> levels 2,3 (LDS)
    const int   l     = ll >> 1;
    const int   W     = 176 >> l;              // 176,88,44,22
    const int   Hh    = 64  >> l;              // 64,32,16,8
    const float wf    = (float)W, hf = (float)Hh;
    const bool  isglb = (l < 2);
    // global: absolute key base (0 / 11264); LDS: staged-index base (0 / 704)
    const int   lvlbase = isglb ? (l == 0 ? 0 : 11264) : (l == 2 ? 0 : 704);
    const int   shmul   = isglb ? 1024 : 128;  // byte stride per key / staged key

    // Replicate reference FP sequence exactly:
    // g = 2*loc - 1; x = ((g+1)*w)*0.5 - 0.5; ix = rint(x) (half-to-even)
    auto compute2 = [&](const f32x4 Lv, int* kp) {
        #pragma unroll
        for (int j = 0; j < 2; ++j) {
            const float px = j ? Lv.z : Lv.x;
            const float py = j ? Lv.w : Lv.y;
            const float gx = 2.0f * px - 1.0f;
            const float gy = 2.0f * py - 1.0f;
            const float x  = ((gx + 1.0f) * wf) * 0.5f - 0.5f;
            const float y  = ((gy + 1.0f) * hf) * 0.5f - 0.5f;
            const float fx = rintf(x);
            const float fy = rintf(y);
            const int ix = (int)fx;
            const int iy = (int)fy;
            const bool valid = (ix >= 0) & (ix < W) & (iy >= 0) & (iy < Hh);
            const int cx = min(max(ix, 0), W - 1);
            const int cy = min(max(iy, 0), Hh - 1);
            // offsets are 1024B/128B aligned -> bit0 carries validity
            kp[j] = (lvlbase + cy * W + cx) * shmul + (valid ? 1 : 0);
        }
    };

    auto locAddr = [&](int qi) {
        const int q = qbase + qi * 64 + gr;
        return (const f32x4*)(loc + ((size_t)(b * NQ + q) * NH + h) * 32 + ll * 4);
    };

    const int srcbase = lane & 56;     // first lane of this 8-lane group
    const char* vlane = vb + vbh + ll * 16;          // + key*1024
    const char* lbase = (const char*)lds + ll * 16;  // + ki*128

    // ---- prologue: loc(0), loc(1); offsets + gathers for step 0 ----
    f32x4 Lnext = __builtin_nontemporal_load(locAddr(0));
    f32x4 Lfar  = __builtin_nontemporal_load(locAddr(1));
    int   koG[8], koL[8];
    float wG[8], wL[8];
    {
        int kp[2];
        compute2(Lnext, kp);
        #pragma unroll
        for (int s = 0; s < 16; ++s) {
            const int a = __shfl(kp[s & 1], srcbase + (s >> 1), 64);
            if (s < 8) { koG[s]     = a & ~1; wG[s]     = (float)(a & 1); }
            else       { koL[s - 8] = a & ~1; wL[s - 8] = (float)(a & 1); }
        }
    }
    Lnext = Lfar;
    f32x4 vg[8];
    #pragma unroll
    for (int s = 0; s < 8; ++s)
        vg[s] = *(const f32x4*)(vlane + (unsigned)koG[s]);

    // ---- main loop: Q=25 steps, depth-1 gather / depth-2 loc pipeline ----
    #pragma unroll 1
    for (int qi = 0; qi < QPT; ++qi) {
        // A: LDS reads for current step (levels 2,3)
        f32x4 vl[8];
        #pragma unroll
        for (int s = 0; s < 8; ++s)
            vl[s] = *(const f32x4*)(lbase + (unsigned)koL[s]);

        // B: compute next step's offsets (VALU+shfl, covers gather latency)
        int   koG2[8], koL2[8];
        float wG2[8], wL2[8];
        if (qi + 1 < QPT) {
            int kp[2];
            compute2(Lnext, kp);
            #pragma unroll
            for (int s = 0; s < 16; ++s) {
                const int a = __shfl(kp[s & 1], srcbase + (s >> 1), 64);
                if (s < 8) { koG2[s]     = a & ~1; wG2[s]     = (float)(a & 1); }
                else       { koL2[s - 8] = a & ~1; wL2[s - 8] = (float)(a & 1); }
            }
        }

        // C: loc prefetch depth-2
        if (qi + 2 < QPT) Lfar = __builtin_nontemporal_load(locAddr(qi + 2));

        // D: consume in reference order s=0..15 (lvl-major, point order).
        // fma(v,1,acc)==acc+v and fma(v,0,acc)==acc exactly.
        f32x4 acc = {0.f, 0.f, 0.f, 0.f};
        #pragma unroll
        for (int s = 0; s < 8; ++s) {
            acc.x = fmaf(vg[s].x, wG[s], acc.x);
            acc.y = fmaf(vg[s].y, wG[s], acc.y);
            acc.z = fmaf(vg[s].z, wG[s], acc.z);
            acc.w = fmaf(vg[s].w, wG[s], acc.w);
        }
        #pragma unroll
        for (int s = 0; s < 8; ++s) {
            acc.x = fmaf(vl[s].x, wL[s], acc.x);
            acc.y = fmaf(vl[s].y, wL[s], acc.y);
            acc.z = fmaf(vl[s].z, wL[s], acc.z);
            acc.w = fmaf(vl[s].w, wL[s], acc.w);
        }

        // E: store (write-once stream)
        const int q = qbase + qi * 64 + gr;
        __builtin_nontemporal_store(acc,
            (f32x4*)(out + ((size_t)(b * NQ + q) * NH + h) * 32 + ll * 4));

        // F: rotate + issue next step's global gathers
        if (qi + 1 < QPT) {
            #pragma unroll
            for (int s = 0; s < 8; ++s) {
                koG[s] = koG2[s]; wG[s] = wG2[s];
                koL[s] = koL2[s]; wL[s] = wL2[s];
            }
            #pragma unroll
            for (int s = 0; s < 8; ++s)
                vg[s] = *(const f32x4*)(vlane + (unsigned)koG[s]);
            Lnext = Lfar;
        }
    }
}

extern "C" void kernel_launch(void* const* d_in, const int* in_sizes, int n_in,
                              void* d_out, int out_size, void* d_ws, size_t ws_size,
                              hipStream_t stream) {
    const float* value = (const float*)d_in[0];
    // d_in[1] = value_spatial_shapes (int32) — constants, hardcoded in-kernel
    const float* loc   = (const float*)d_in[2];
    float* out = (float*)d_out;

    // grid = 8 xcd * 6 b * 25 chunks = 1200 blocks * 512 threads,
    // 112,640 B dynamic LDS (levels 2+3 slice of one (b,h))
    msda_kernel<<<1200, THREADS, STAGE_KEYS * 128, stream>>>(value, loc, out);
}